// Round 3
// baseline (438.014 us; speedup 1.0000x reference)
//
#include <hip/hip_runtime.h>
#include <hip/hip_bf16.h>
#include <stdint.h>

// B=8 L=8192 C=384 DIN=128 HID=512, tokens=65536, bands(16 tok)=4096.
// softmax over size-1 axis == 1 -> attention out == v -> fold Wc = Wv@Wp.
// z = y + gelu(LN2(y)@W1+bm1)@W2 + bm2,  y = LN1(x)@Wc + bc.
// R3: all kernels barrier-free after init staging; k1 loads A-frags straight
// from global (no A1 LDS, no tile barrier); k2 split into two half-hidden
// weight-resident kernels; tanh-form gelu (v_exp+v_rcp, ~8 VALU).

typedef __attribute__((ext_vector_type(8))) short bf16x8;
typedef __attribute__((ext_vector_type(4))) float f32x4;

__device__ __forceinline__ short f2bf(float f) {
  union { float f; unsigned u; } a; a.f = f;
  unsigned u = a.u;
  u += 0x7fffu + ((u >> 16) & 1u);   // RNE, finite inputs
  return (short)(u >> 16);
}
__device__ __forceinline__ float bf2f(short s) {
  union { unsigned u; float f; } a; a.u = ((unsigned)(unsigned short)s) << 16;
  return a.f;
}
__device__ __forceinline__ float gelu_fast(float h) {
  // 0.5h(1+tanh(u)) = h*sigmoid(2u), 2u*log2(e) = h*(2.3022082 + 0.1029471*h^2)
  float h2 = h * h;
  float w  = h * (2.3022082f + 0.1029471f * h2);
  float e  = __builtin_amdgcn_exp2f(w);          // e^(2u)
  float r  = __builtin_amdgcn_rcpf(e + 1.0f);
  return h - h * r;                               // h*(1 - 1/(1+e)) = h*sig(2u)
}
__device__ __forceinline__ void gload_lds16(const void* g, void* l) {
  __builtin_amdgcn_global_load_lds(
      (const __attribute__((address_space(1))) unsigned*)g,
      (__attribute__((address_space(3))) unsigned*)l, 16, 0, 0);
}

// ws layout (bytes):
//   WcT  [128][392]bf16 @ 0        (100352)
//   W1Ta [256][132]bf16 @ 100352   (67584)
//   W2Ta [4][128][68]   @ 167936   (69632)
//   W1Tb [256][132]     @ 237568   (67584)
//   W2Tb [4][128][68]   @ 305152   (69632)
//   bc   [128]f32       @ 374784
//   ybuf [4096][2048]   @ 376832   (16 MB)  y then y+partial1 (bf16, (r,q,c16,t))
//   lb   [4096][2048]   @ 17154048 (16 MB)  ln2(y) (bf16, frag-major c16-fastest)

// ---------------- prep --------------------------------------------------------
__global__ void prep(const float* __restrict__ Wkv, const float* __restrict__ bkv,
                     const float* __restrict__ Wp,  const float* __restrict__ bp,
                     const float* __restrict__ W1,  const float* __restrict__ W2,
                     short* __restrict__ WcT, short* __restrict__ W1Ta,
                     short* __restrict__ W1Tb, short* __restrict__ W2Ta,
                     short* __restrict__ W2Tb, float* __restrict__ bc) {
  const int b = blockIdx.x, tid = threadIdx.x;
  if (b < 192) {                       // WcT fold: k = 2b+(tid>>7), n = tid&127
    __shared__ float wv[2][128];
    const int kk = tid >> 7, n = tid & 127;
    wv[kk][n] = Wkv[(2 * b + kk) * 256 + 128 + n];
    __syncthreads();
    float s0 = 0, s1 = 0, s2 = 0, s3 = 0;
#pragma unroll 8
    for (int m = 0; m < 128; m += 4) {
      s0 += wv[kk][m]     * Wp[(m)     * 128 + n];
      s1 += wv[kk][m + 1] * Wp[(m + 1) * 128 + n];
      s2 += wv[kk][m + 2] * Wp[(m + 2) * 128 + n];
      s3 += wv[kk][m + 3] * Wp[(m + 3) * 128 + n];
    }
    WcT[n * 392 + (2 * b + kk)] = f2bf(s0 + s1 + s2 + s3);
  } else if (b == 192) {
    if (tid < 128) {
      float s = bp[tid];
#pragma unroll 8
      for (int m = 0; m < 128; ++m) s += bkv[128 + m] * Wp[m * 128 + tid];
      bc[tid] = s;
    }
  } else if (b < 449) {                // W1 transpose halves
    const int id = (b - 193) * 256 + tid;
    const int n = id & 511, k = id >> 9;
    const short v = f2bf(W1[k * 512 + n]);
    if (n < 256) W1Ta[n * 132 + k] = v;
    else         W1Tb[(n - 256) * 132 + k] = v;
  } else {                             // W2 transpose, ch-chunked halves
    const int id = (b - 449) * 256 + tid;
    const int n = id & 127, k = id >> 7;
    const int ch = k >> 6, kk = k & 63;
    const short v = f2bf(W2[k * 128 + n]);
    short* dst = (ch < 4) ? W2Ta : W2Tb;
    dst[((ch & 3) * 128 + n) * 68 + kk] = v;
  }
}

// ---------------- K1: LN1 + y-GEMM + LN2, barrier-free waves -----------------
__global__ __launch_bounds__(512, 2)
void k1(const float* __restrict__ x,  const float* __restrict__ g1,
        const float* __restrict__ b1, const float* __restrict__ g2,
        const float* __restrict__ b2,
        const short* __restrict__ WcTg, const float* __restrict__ bcg,
        short* __restrict__ yb, short* __restrict__ lb) {
  __shared__ __align__(16) short WcT_l[128 * 392];   // 100352 B
  __shared__ __align__(16) float g1s[384], b1s[384], bcf[128], g2f[128], b2f[128];
  const int tid = threadIdx.x, lane = tid & 63, w = tid >> 6;
  const int q = lane >> 4, c16 = lane & 15;

  for (int c = w; c < 98; c += 8)          // stage WcT once (98 x 1 KB)
    gload_lds16((const char*)WcTg + c * 1024 + lane * 16, (char*)WcT_l + c * 1024);
  if (tid < 96)       ((float4*)g1s)[tid]       = ((const float4*)g1)[tid];
  else if (tid < 192) ((float4*)b1s)[tid - 96]  = ((const float4*)b1)[tid - 96];
  else if (tid < 224) ((float4*)bcf)[tid - 192] = ((const float4*)bcg)[tid - 192];
  else if (tid < 256) ((float4*)g2f)[tid - 224] = ((const float4*)g2)[tid - 224];
  else if (tid < 288) ((float4*)b2f)[tid - 256] = ((const float4*)b2)[tid - 256];
  __syncthreads();   // only barrier in the kernel

  // per-lane hoists (c16 fixed)
  float bcv[8], g2v[8], b2v[8];
#pragma unroll
  for (int t = 0; t < 8; ++t) {
    bcv[t] = bcf[t * 16 + c16]; g2v[t] = g2f[t * 16 + c16]; b2v[t] = b2f[t * 16 + c16];
  }

  const int gw = blockIdx.x * 8 + w;
  for (int i = 0; i < 2; ++i) {
    const long band = (long)gw * 2 + i;
    // ---- load A-frag slice of x directly: lane(c16,q) k = ks*32+q*8+[0,8)
    const float* xp = x + (band * 16 + c16) * 384 + q * 8;
    float4 xa[24];
#pragma unroll
    for (int ks = 0; ks < 12; ++ks) {
      xa[2 * ks]     = *(const float4*)(xp + ks * 32);
      xa[2 * ks + 1] = *(const float4*)(xp + ks * 32 + 4);
    }
    float s = 0.f, sq = 0.f;
#pragma unroll
    for (int u = 0; u < 24; ++u) {
      float4 v = xa[u];
      s  += v.x + v.y + v.z + v.w;
      sq += v.x * v.x + v.y * v.y + v.z * v.z + v.w * v.w;
    }
    s  += __shfl_xor(s, 16);  s  += __shfl_xor(s, 32);   // reduce across q
    sq += __shfl_xor(sq, 16); sq += __shfl_xor(sq, 32);
    const float mean = s * (1.f / 384.f);
    const float rs = rsqrtf(sq * (1.f / 384.f) - mean * mean + 1e-5f);
    // ---- build bf16 A-frags in registers
    bf16x8 frag[12];
#pragma unroll
    for (int ks = 0; ks < 12; ++ks) {
      const float4 ga = *(const float4*)(g1s + ks * 32 + q * 8);
      const float4 gb = *(const float4*)(g1s + ks * 32 + q * 8 + 4);
      const float4 ba = *(const float4*)(b1s + ks * 32 + q * 8);
      const float4 bb = *(const float4*)(b1s + ks * 32 + q * 8 + 4);
      const float4 va = xa[2 * ks], vb = xa[2 * ks + 1];
      bf16x8 f;
      f[0] = f2bf((va.x - mean) * rs * ga.x + ba.x);
      f[1] = f2bf((va.y - mean) * rs * ga.y + ba.y);
      f[2] = f2bf((va.z - mean) * rs * ga.z + ba.z);
      f[3] = f2bf((va.w - mean) * rs * ga.w + ba.w);
      f[4] = f2bf((vb.x - mean) * rs * gb.x + bb.x);
      f[5] = f2bf((vb.y - mean) * rs * gb.y + bb.y);
      f[6] = f2bf((vb.z - mean) * rs * gb.z + bb.z);
      f[7] = f2bf((vb.w - mean) * rs * gb.w + bb.w);
      frag[ks] = f;
    }
    // ---- y = LN1(x) @ Wc  (B-frags from LDS)
    f32x4 yacc[8];
#pragma unroll
    for (int t = 0; t < 8; ++t) yacc[t] = (f32x4){0.f, 0.f, 0.f, 0.f};
#pragma unroll
    for (int ks = 0; ks < 12; ++ks)
#pragma unroll
      for (int t = 0; t < 8; ++t) {
        bf16x8 bfr = *(const bf16x8*)(WcT_l + (t * 16 + c16) * 392 + ks * 32 + q * 8);
        yacc[t] = __builtin_amdgcn_mfma_f32_16x16x32_bf16(frag[ks], bfr, yacc[t], 0, 0, 0);
      }
    // ---- +bc, LN2 stats (rows=(q,r); reduce over c16 lanes)
    float sm[4] = {0, 0, 0, 0}, sv[4] = {0, 0, 0, 0};
#pragma unroll
    for (int t = 0; t < 8; ++t)
#pragma unroll
      for (int r = 0; r < 4; ++r) {
        yacc[t][r] += bcv[t];
        const float v = yacc[t][r]; sm[r] += v; sv[r] += v * v;
      }
#pragma unroll
    for (int r = 0; r < 4; ++r) {
      sm[r] += __shfl_xor(sm[r], 1); sm[r] += __shfl_xor(sm[r], 2);
      sm[r] += __shfl_xor(sm[r], 4); sm[r] += __shfl_xor(sm[r], 8);
      sv[r] += __shfl_xor(sv[r], 1); sv[r] += __shfl_xor(sv[r], 2);
      sv[r] += __shfl_xor(sv[r], 4); sv[r] += __shfl_xor(sv[r], 8);
    }
    // ---- store y (t-fastest, b128) and ln2y (c16-fastest frag-major)
    short* ybB = yb + band * 2048;
    short* lbB = lb + band * 2048;
#pragma unroll
    for (int r = 0; r < 4; ++r) {
      const float mn = sm[r] * (1.f / 128.f);
      const float rv = rsqrtf(sv[r] * (1.f / 128.f) - mn * mn + 1e-5f);
      bf16x8 yp;
#pragma unroll
      for (int t = 0; t < 8; ++t) {
        const float yv = yacc[t][r];
        yp[t] = f2bf(yv);
        lbB[((t * 4 + r) * 4 + q) * 16 + c16] = f2bf((yv - mn) * rv * g2v[t] + b2v[t]);
      }
      *(bf16x8*)(ybB + ((r * 4 + q) * 16 + c16) * 8) = yp;
    }
  }
}

// ---------------- K2 halves: hidden-chunk MLP, weight-resident, barrier-free -
template <bool FINAL>
__global__ __launch_bounds__(512, 2)
void k2(const short* __restrict__ lb, short* __restrict__ ybuf,
        const short* __restrict__ W1Tg, const short* __restrict__ W2Tg,
        const float* __restrict__ bm1h, const float* __restrict__ bm2,
        float* __restrict__ out) {
  __shared__ __align__(16) short W1s[256 * 132];   // 67584 B
  __shared__ __align__(16) short W2s[4 * 128 * 68];// 69632 B
  __shared__ __align__(16) short A3s[8][16 * 68];  // 17408 B, wave-private
  __shared__ float bm1s[256], bm2s[128];
  const int tid = threadIdx.x, lane = tid & 63, w = tid >> 6;
  const int q = lane >> 4, c16 = lane & 15;

  for (int c = w; c < 66; c += 8)
    gload_lds16((const char*)W1Tg + c * 1024 + lane * 16, (char*)W1s + c * 1024);
  for (int c = w; c < 68; c += 8)
    gload_lds16((const char*)W2Tg + c * 1024 + lane * 16, (char*)W2s + c * 1024);
  if (tid < 64) ((float4*)bm1s)[tid] = ((const float4*)bm1h)[tid];
  else if (tid < 96) ((float4*)bm2s)[tid - 64] = ((const float4*)bm2)[tid - 64];
  __syncthreads();   // only barrier

  float bm2v[8];
#pragma unroll
  for (int t = 0; t < 8; ++t) bm2v[t] = bm2s[t * 16 + c16];

  const int gw = blockIdx.x * 8 + w;
  for (int i = 0; i < 2; ++i) {
    const long band = (long)gw * 2 + i;
    const short* lbB = lb + band * 2048;
    short* ybB = ybuf + band * 2048;
    // A2 frags (ln2y) — contiguous b128 reads from frag-major layout
    bf16x8 a2f[4];
#pragma unroll
    for (int ks = 0; ks < 4; ++ks) {
      const int t = ks * 2 + (q >> 1);
      a2f[ks] = *(const bf16x8*)(lbB + ((t * 4 + (c16 & 3)) * 4 + (c16 >> 2)) * 16 + (q & 1) * 8);
    }
    bf16x8 yf[4];
#pragma unroll
    for (int r = 0; r < 4; ++r)
      yf[r] = *(const bf16x8*)(ybB + ((r * 4 + q) * 16 + c16) * 8);

    f32x4 zacc[8];
#pragma unroll
    for (int t = 0; t < 8; ++t) zacc[t] = (f32x4){0.f, 0.f, 0.f, 0.f};

#pragma unroll
    for (int ch = 0; ch < 4; ++ch) {
      f32x4 hacc[4];
#pragma unroll
      for (int tt = 0; tt < 4; ++tt) hacc[tt] = (f32x4){0.f, 0.f, 0.f, 0.f};
#pragma unroll
      for (int ks = 0; ks < 4; ++ks)
#pragma unroll
        for (int tt = 0; tt < 4; ++tt) {
          bf16x8 bfr = *(const bf16x8*)(W1s + (ch * 64 + tt * 16 + c16) * 132 + ks * 32 + q * 8);
          hacc[tt] = __builtin_amdgcn_mfma_f32_16x16x32_bf16(a2f[ks], bfr, hacc[tt], 0, 0, 0);
        }
      short* a3 = A3s[w];
#pragma unroll
      for (int tt = 0; tt < 4; ++tt) {
        const float bb = bm1s[ch * 64 + tt * 16 + c16];
#pragma unroll
        for (int r = 0; r < 4; ++r) {
          const float h = hacc[tt][r] + bb;
          a3[(q * 4 + r) * 68 + tt * 16 + c16] = f2bf(gelu_fast(h));
        }
      }
      asm volatile("s_waitcnt lgkmcnt(0)" ::: "memory");  // in-wave A3 RAW
#pragma unroll
      for (int ks = 0; ks < 2; ++ks) {
        bf16x8 af = *(const bf16x8*)(a3 + c16 * 68 + ks * 32 + q * 8);
#pragma unroll
        for (int t = 0; t < 8; ++t) {
          bf16x8 bfr = *(const bf16x8*)(W2s + (ch * 128 + t * 16 + c16) * 68 + ks * 32 + q * 8);
          zacc[t] = __builtin_amdgcn_mfma_f32_16x16x32_bf16(af, bfr, zacc[t], 0, 0, 0);
        }
      }
    }
    if (!FINAL) {      // k2a: ybuf = y + partial1 (bf16 RMW, own band only)
#pragma unroll
      for (int r = 0; r < 4; ++r) {
        bf16x8 zp;
#pragma unroll
        for (int t = 0; t < 8; ++t) zp[t] = f2bf(bf2f(yf[r][t]) + zacc[t][r]);
        *(bf16x8*)(ybB + ((r * 4 + q) * 16 + c16) * 8) = zp;
      }
    } else {           // k2b: out = (y+partial1) + partial2 + bm2
#pragma unroll
      for (int r = 0; r < 4; ++r) {
        const long rowg = band * 16 + q * 4 + r;
#pragma unroll
        for (int t = 0; t < 8; ++t)
          out[rowg * 128 + t * 16 + c16] = bf2f(yf[r][t]) + zacc[t][r] + bm2v[t];
      }
    }
  }
}

extern "C" void kernel_launch(void* const* d_in, const int* in_sizes, int n_in,
                              void* d_out, int out_size, void* d_ws, size_t ws_size,
                              hipStream_t stream) {
  const float* x   = (const float*)d_in[0];
  const float* g1  = (const float*)d_in[1];
  const float* b1  = (const float*)d_in[2];
  // d_in[3]=Wq, [4]=bq, [7]=rpb dead (softmax over size-1 axis == 1)
  const float* Wkv = (const float*)d_in[5];
  const float* bkv = (const float*)d_in[6];
  const float* Wp  = (const float*)d_in[8];
  const float* bp  = (const float*)d_in[9];
  const float* g2  = (const float*)d_in[10];
  const float* b2  = (const float*)d_in[11];
  const float* W1  = (const float*)d_in[12];
  const float* bm1 = (const float*)d_in[13];
  const float* W2  = (const float*)d_in[14];
  const float* bm2 = (const float*)d_in[15];

  char* ws = (char*)d_ws;
  short* WcT  = (short*)(ws + 0);
  short* W1Ta = (short*)(ws + 100352);
  short* W2Ta = (short*)(ws + 167936);
  short* W1Tb = (short*)(ws + 237568);
  short* W2Tb = (short*)(ws + 305152);
  float* bc   = (float*)(ws + 374784);
  short* ybuf = (short*)(ws + 376832);
  short* lb   = (short*)(ws + 17154048);

  prep<<<705, 256, 0, stream>>>(Wkv, bkv, Wp, bp, W1, W2,
                                WcT, W1Ta, W1Tb, W2Ta, W2Tb, bc);
  k1<<<256, 512, 0, stream>>>(x, g1, b1, g2, b2, WcT, bc, ybuf, lb);
  k2<false><<<256, 512, 0, stream>>>(lb, ybuf, W1Ta, W2Ta, bm1, bm2, (float*)d_out);
  k2<true><<<256, 512, 0, stream>>>(lb, ybuf, W1Tb, W2Tb, bm1 + 256, bm2, (float*)d_out);
}

// Round 4
// 255.963 us; speedup vs baseline: 1.7112x; 1.7112x over previous
//
#include <hip/hip_runtime.h>
#include <hip/hip_bf16.h>
#include <stdint.h>

// B=8 L=8192 C=384 DIN=128 HID=512, tokens=65536, bands(16 tok)=4096.
// softmax over size-1 axis == 1 -> attention out == v -> fold Wc = Wv@Wp.
// z = y + gelu(LN2(y)@W1+bm1)@W2 + bm2,  y = LN1(x)@Wc + bc.
// R4: LN gains/biases folded into weights at prep; k1 converts x->bf16
// immediately (no fp32 x in regs => no spill); 1024-thread blocks everywhere
// (4 waves/SIMD); k2 MLP in 32-hidden sub-chunks to shorten serial chains.

typedef __attribute__((ext_vector_type(8))) short bf16x8;
typedef __attribute__((ext_vector_type(4))) float f32x4;

__device__ __forceinline__ short f2bf(float f) {
  union { float f; unsigned u; } a; a.f = f;
  unsigned u = a.u;
  u += 0x7fffu + ((u >> 16) & 1u);   // RNE, finite inputs
  return (short)(u >> 16);
}
__device__ __forceinline__ float bf2f(short s) {
  union { unsigned u; float f; } a; a.u = ((unsigned)(unsigned short)s) << 16;
  return a.f;
}
__device__ __forceinline__ float gelu_fast(float h) {
  // 0.5h(1+tanh(u)) = h*sigmoid(2u); 2u*log2e = h*(2.3022082+0.1029471h^2)
  float h2 = h * h;
  float w  = h * (2.3022082f + 0.1029471f * h2);
  float e  = __builtin_amdgcn_exp2f(w);
  float r  = __builtin_amdgcn_rcpf(e + 1.0f);
  return h - h * r;
}
__device__ __forceinline__ void gload_lds16(const void* g, void* l) {
  __builtin_amdgcn_global_load_lds(
      (const __attribute__((address_space(1))) unsigned*)g,
      (__attribute__((address_space(3))) unsigned*)l, 16, 0, 0);
}

// ws layout (1024-aligned staged arrays):
//   WcT  [128][392] @0         (100352)  rows pre-scaled... cols: Wc[k][n]*g1[k]
//   W1Ta [256][132] @100352    (67584)   W1[k][n]*g2[k], n<256
//   W2Ta [4][128][68] @167936  (69632)
//   W1Tb [256][132] @237568    (67584)   n in [256,512)
//   W2Tb [4][128][68] @305152  (69632)
//   bc   [128]f32  @374784     bp + (bkv_v + b1@Wv)@Wp
//   bm1c [512]f32  @375296     bm1 + b2@W1
//   ybuf [4096][2048]bf16 @378880    y, then y+partial1
//   lb   [4096][2048]bf16 @17156096  (y-m2)*rsig2 (unscaled LN2), frag-major

// ---------------- prep (707 blocks x 256) ------------------------------------
__global__ void prep(const float* __restrict__ Wkv, const float* __restrict__ bkv,
                     const float* __restrict__ Wp,  const float* __restrict__ bp,
                     const float* __restrict__ W1,  const float* __restrict__ W2,
                     const float* __restrict__ g1,  const float* __restrict__ b1,
                     const float* __restrict__ g2,  const float* __restrict__ b2,
                     const float* __restrict__ bm1,
                     short* __restrict__ WcT, short* __restrict__ W1Ta,
                     short* __restrict__ W1Tb, short* __restrict__ W2Ta,
                     short* __restrict__ W2Tb, float* __restrict__ bc,
                     float* __restrict__ bm1c) {
  const int b = blockIdx.x, tid = threadIdx.x;
  if (b < 192) {                        // WcT fold + g1 scale
    __shared__ float wv[2][128];
    const int kk = tid >> 7, n = tid & 127, k = 2 * b + kk;
    wv[kk][n] = Wkv[k * 256 + 128 + n];
    __syncthreads();
    float s0 = 0, s1 = 0, s2 = 0, s3 = 0;
#pragma unroll 8
    for (int m = 0; m < 128; m += 4) {
      s0 += wv[kk][m]     * Wp[(m)     * 128 + n];
      s1 += wv[kk][m + 1] * Wp[(m + 1) * 128 + n];
      s2 += wv[kk][m + 2] * Wp[(m + 2) * 128 + n];
      s3 += wv[kk][m + 3] * Wp[(m + 3) * 128 + n];
    }
    WcT[n * 392 + k] = f2bf(g1[k] * (s0 + s1 + s2 + s3));
  } else if (b == 192) {                // bc = bp + (bkv_v + b1@Wv)@Wp
    __shared__ float t[128];
    if (tid < 128) {
      float a = 0;
      for (int k = 0; k < 384; ++k) a += b1[k] * Wkv[k * 256 + 128 + tid];
      t[tid] = a + bkv[128 + tid];
    }
    __syncthreads();
    if (tid < 128) {
      float s = bp[tid];
#pragma unroll 8
      for (int m = 0; m < 128; ++m) s += t[m] * Wp[m * 128 + tid];
      bc[tid] = s;
    }
  } else if (b < 449) {                 // W1T halves, rows scaled by g2[k]
    const int id = (b - 193) * 256 + tid;
    const int n = id & 511, k = id >> 9;
    const short v = f2bf(W1[k * 512 + n] * g2[k]);
    if (n < 256) W1Ta[n * 132 + k] = v;
    else         W1Tb[(n - 256) * 132 + k] = v;
  } else if (b < 705) {                 // W2T, ch-chunked halves
    const int id = (b - 449) * 256 + tid;
    const int n = id & 127, k = id >> 7;
    const int ch = k >> 6, kk = k & 63;
    short* dst = (ch < 4) ? W2Ta : W2Tb;
    dst[((ch & 3) * 128 + n) * 68 + kk] = f2bf(W2[k * 128 + n]);
  } else {                              // bm1c = bm1 + b2@W1
    const int h = (b - 705) * 256 + tid;   // [0,512)
    float s = bm1[h];
#pragma unroll 8
    for (int k = 0; k < 128; ++k) s += b2[k] * W1[k * 512 + h];
    bm1c[h] = s;
  }
}

// ---------------- K1: LN1 + y-GEMM + LN2 (unscaled), 16 waves/block ----------
__global__ __launch_bounds__(1024, 4)
void k1(const float* __restrict__ x, const short* __restrict__ WcTg,
        const float* __restrict__ bcg,
        short* __restrict__ yb, short* __restrict__ lb) {
  __shared__ __align__(16) short WcT_l[128 * 392];   // 100352 B
  __shared__ float bcf[128];
  const int tid = threadIdx.x, lane = tid & 63, w = tid >> 6;
  const int q = lane >> 4, c16 = lane & 15;

  for (int c = w; c < 98; c += 16)
    gload_lds16((const char*)WcTg + c * 1024 + lane * 16, (char*)WcT_l + c * 1024);
  if (tid < 32) ((float4*)bcf)[tid] = ((const float4*)bcg)[tid];
  __syncthreads();   // only barrier

  float bcv[8];
#pragma unroll
  for (int t = 0; t < 8; ++t) bcv[t] = bcf[t * 16 + c16];

  const long band = (long)blockIdx.x * 16 + w;
  const float* xp = x + (band * 16 + c16) * 384 + q * 8;
  // ---- stream x: stats in fp32, stash values as bf16 immediately (no spill)
  bf16x8 frag[12];
  float s = 0.f, sq = 0.f;
#pragma unroll
  for (int ks = 0; ks < 12; ++ks) {
    const float4 va = *(const float4*)(xp + ks * 32);
    const float4 vb = *(const float4*)(xp + ks * 32 + 4);
    s  += va.x + va.y + va.z + va.w + vb.x + vb.y + vb.z + vb.w;
    sq += va.x * va.x + va.y * va.y + va.z * va.z + va.w * va.w
        + vb.x * vb.x + vb.y * vb.y + vb.z * vb.z + vb.w * vb.w;
    bf16x8 f;
    f[0] = f2bf(va.x); f[1] = f2bf(va.y); f[2] = f2bf(va.z); f[3] = f2bf(va.w);
    f[4] = f2bf(vb.x); f[5] = f2bf(vb.y); f[6] = f2bf(vb.z); f[7] = f2bf(vb.w);
    frag[ks] = f;
  }
  s  += __shfl_xor(s, 16);  s  += __shfl_xor(s, 32);
  sq += __shfl_xor(sq, 16); sq += __shfl_xor(sq, 32);
  const float mean = s * (1.f / 384.f);
  const float rs = rsqrtf(sq * (1.f / 384.f) - mean * mean + 1e-5f);
#pragma unroll
  for (int ks = 0; ks < 12; ++ks) {
    bf16x8 f = frag[ks];
#pragma unroll
    for (int e = 0; e < 8; ++e) f[e] = f2bf((bf2f(f[e]) - mean) * rs);
    frag[ks] = f;
  }
  // ---- y = norm(x) @ WcT(g1-folded)
  f32x4 yacc[8];
#pragma unroll
  for (int t = 0; t < 8; ++t) yacc[t] = (f32x4){0.f, 0.f, 0.f, 0.f};
#pragma unroll
  for (int ks = 0; ks < 12; ++ks)
#pragma unroll
    for (int t = 0; t < 8; ++t) {
      bf16x8 bfr = *(const bf16x8*)(WcT_l + (t * 16 + c16) * 392 + ks * 32 + q * 8);
      yacc[t] = __builtin_amdgcn_mfma_f32_16x16x32_bf16(frag[ks], bfr, yacc[t], 0, 0, 0);
    }
  // ---- +bc, LN2 stats (rows=(q,r), reduce over c16 lanes)
  float sm[4] = {0, 0, 0, 0}, sv[4] = {0, 0, 0, 0};
#pragma unroll
  for (int t = 0; t < 8; ++t)
#pragma unroll
    for (int r = 0; r < 4; ++r) {
      yacc[t][r] += bcv[t];
      const float v = yacc[t][r]; sm[r] += v; sv[r] += v * v;
    }
#pragma unroll
  for (int r = 0; r < 4; ++r) {
    sm[r] += __shfl_xor(sm[r], 1); sm[r] += __shfl_xor(sm[r], 2);
    sm[r] += __shfl_xor(sm[r], 4); sm[r] += __shfl_xor(sm[r], 8);
    sv[r] += __shfl_xor(sv[r], 1); sv[r] += __shfl_xor(sv[r], 2);
    sv[r] += __shfl_xor(sv[r], 4); sv[r] += __shfl_xor(sv[r], 8);
  }
  short* ybB = yb + band * 2048;
  short* lbB = lb + band * 2048;
#pragma unroll
  for (int r = 0; r < 4; ++r) {
    const float mn = sm[r] * (1.f / 128.f);
    const float rv = rsqrtf(sv[r] * (1.f / 128.f) - mn * mn + 1e-5f);
    bf16x8 yp;
#pragma unroll
    for (int t = 0; t < 8; ++t) {
      const float yv = yacc[t][r];
      yp[t] = f2bf(yv);
      lbB[((t * 4 + r) * 4 + q) * 16 + c16] = f2bf((yv - mn) * rv);  // g2/b2 folded
    }
    *(bf16x8*)(ybB + ((r * 4 + q) * 16 + c16) * 8) = yp;
  }
}

// ---------------- K2 halves: MLP in 32-hidden sub-chunks, 16 waves/block -----
template <bool FINAL>
__global__ __launch_bounds__(1024, 4)
void k2(const short* __restrict__ lb, short* __restrict__ ybuf,
        const short* __restrict__ W1Tg, const short* __restrict__ W2Tg,
        const float* __restrict__ bm1h, const float* __restrict__ bm2,
        float* __restrict__ out) {
  __shared__ __align__(16) short W1s[256 * 132];    // 67584 B
  __shared__ __align__(16) short W2s[4 * 128 * 68]; // 69632 B
  __shared__ __align__(16) short A3s[16][16 * 36];  // 18432 B, wave-private
  __shared__ float bm1s[256], bm2s[128];
  const int tid = threadIdx.x, lane = tid & 63, w = tid >> 6;
  const int q = lane >> 4, c16 = lane & 15;

  for (int c = w; c < 66; c += 16)
    gload_lds16((const char*)W1Tg + c * 1024 + lane * 16, (char*)W1s + c * 1024);
  for (int c = w; c < 68; c += 16)
    gload_lds16((const char*)W2Tg + c * 1024 + lane * 16, (char*)W2s + c * 1024);
  if (tid < 64) ((float4*)bm1s)[tid] = ((const float4*)bm1h)[tid];
  else if (tid < 96) ((float4*)bm2s)[tid - 64] = ((const float4*)bm2)[tid - 64];
  __syncthreads();   // only barrier

  float bm2v[8];
#pragma unroll
  for (int t = 0; t < 8; ++t) bm2v[t] = bm2s[t * 16 + c16];

  const long band = (long)blockIdx.x * 16 + w;
  const short* lbB = lb + band * 2048;
  short* ybB = ybuf + band * 2048;
  bf16x8 a2f[4];
#pragma unroll
  for (int ks = 0; ks < 4; ++ks) {
    const int t = ks * 2 + (q >> 1);
    a2f[ks] = *(const bf16x8*)(lbB + ((t * 4 + (c16 & 3)) * 4 + (c16 >> 2)) * 16 + (q & 1) * 8);
  }
  f32x4 zacc[8];
#pragma unroll
  for (int t = 0; t < 8; ++t) zacc[t] = (f32x4){0.f, 0.f, 0.f, 0.f};
  short* a3 = A3s[w];

#pragma unroll
  for (int ch = 0; ch < 4; ++ch) {
#pragma unroll
    for (int sub = 0; sub < 2; ++sub) {
      f32x4 hacc[2];
      hacc[0] = (f32x4){0.f, 0.f, 0.f, 0.f};
      hacc[1] = (f32x4){0.f, 0.f, 0.f, 0.f};
#pragma unroll
      for (int ks = 0; ks < 4; ++ks)
#pragma unroll
        for (int tt = 0; tt < 2; ++tt) {
          bf16x8 bfr = *(const bf16x8*)(W1s + (ch * 64 + sub * 32 + tt * 16 + c16) * 132 + ks * 32 + q * 8);
          hacc[tt] = __builtin_amdgcn_mfma_f32_16x16x32_bf16(a2f[ks], bfr, hacc[tt], 0, 0, 0);
        }
#pragma unroll
      for (int tt = 0; tt < 2; ++tt) {
        const float bb = bm1s[ch * 64 + sub * 32 + tt * 16 + c16];
#pragma unroll
        for (int r = 0; r < 4; ++r) {
          const float h = hacc[tt][r] + bb;
          a3[(q * 4 + r) * 36 + tt * 16 + c16] = f2bf(gelu_fast(h));
        }
      }
      asm volatile("s_waitcnt lgkmcnt(0)" ::: "memory");  // wave-sync A3 RAW
      bf16x8 af = *(const bf16x8*)(a3 + c16 * 36 + q * 8);
#pragma unroll
      for (int t = 0; t < 8; ++t) {
        bf16x8 bfr = *(const bf16x8*)(W2s + (ch * 128 + t * 16 + c16) * 68 + sub * 32 + q * 8);
        zacc[t] = __builtin_amdgcn_mfma_f32_16x16x32_bf16(af, bfr, zacc[t], 0, 0, 0);
      }
    }
  }
  // ---- epilogue
  bf16x8 yf[4];
#pragma unroll
  for (int r = 0; r < 4; ++r)
    yf[r] = *(const bf16x8*)(ybB + ((r * 4 + q) * 16 + c16) * 8);
  if (!FINAL) {        // k2a: ybuf = y + partial1 (bf16 RMW, own band)
#pragma unroll
    for (int r = 0; r < 4; ++r) {
      bf16x8 zp;
#pragma unroll
      for (int t = 0; t < 8; ++t) zp[t] = f2bf(bf2f(yf[r][t]) + zacc[t][r]);
      *(bf16x8*)(ybB + ((r * 4 + q) * 16 + c16) * 8) = zp;
    }
  } else {             // k2b: out = (y+partial1) + partial2 + bm2
#pragma unroll
    for (int r = 0; r < 4; ++r) {
      const long rowg = band * 16 + q * 4 + r;
#pragma unroll
      for (int t = 0; t < 8; ++t)
        out[rowg * 128 + t * 16 + c16] = bf2f(yf[r][t]) + zacc[t][r] + bm2v[t];
    }
  }
}

extern "C" void kernel_launch(void* const* d_in, const int* in_sizes, int n_in,
                              void* d_out, int out_size, void* d_ws, size_t ws_size,
                              hipStream_t stream) {
  const float* x   = (const float*)d_in[0];
  const float* g1  = (const float*)d_in[1];
  const float* b1  = (const float*)d_in[2];
  // d_in[3]=Wq, [4]=bq, [7]=rpb dead (softmax over size-1 axis == 1)
  const float* Wkv = (const float*)d_in[5];
  const float* bkv = (const float*)d_in[6];
  const float* Wp  = (const float*)d_in[8];
  const float* bp  = (const float*)d_in[9];
  const float* g2  = (const float*)d_in[10];
  const float* b2  = (const float*)d_in[11];
  const float* W1  = (const float*)d_in[12];
  const float* bm1 = (const float*)d_in[13];
  const float* W2  = (const float*)d_in[14];
  const float* bm2 = (const float*)d_in[15];

  char* ws = (char*)d_ws;
  short* WcT  = (short*)(ws + 0);
  short* W1Ta = (short*)(ws + 100352);
  short* W2Ta = (short*)(ws + 167936);
  short* W1Tb = (short*)(ws + 237568);
  short* W2Tb = (short*)(ws + 305152);
  float* bc   = (float*)(ws + 374784);
  float* bm1c = (float*)(ws + 375296);
  short* ybuf = (short*)(ws + 378880);
  short* lb   = (short*)(ws + 17156096);

  prep<<<707, 256, 0, stream>>>(Wkv, bkv, Wp, bp, W1, W2, g1, b1, g2, b2, bm1,
                                WcT, W1Ta, W1Tb, W2Ta, W2Tb, bc, bm1c);
  k1<<<256, 1024, 0, stream>>>(x, WcT, bc, ybuf, lb);
  k2<false><<<256, 1024, 0, stream>>>(lb, ybuf, W1Ta, W2Ta, bm1c, bm2, (float*)d_out);
  k2<true><<<256, 1024, 0, stream>>>(lb, ybuf, W1Tb, W2Tb, bm1c + 256, bm2, (float*)d_out);
}

// Round 5
// 253.992 us; speedup vs baseline: 1.7245x; 1.0078x over previous
//
#include <hip/hip_runtime.h>
#include <hip/hip_bf16.h>
#include <stdint.h>

// B=8 L=8192 C=384 DIN=128 HID=512, tokens=65536, bands(16 tok)=4096.
// softmax over size-1 axis == 1 -> attention out == v -> fold Wc = Wv@Wp.
// z = y + gelu(LN2(y)@W1+bm1)@W2 + bm2,  y = LN1(x)@Wc + bc.
// R5: fix launch_bounds VGPR strangle (arg2 acted as blocks/CU -> 64 VGPR ->
// spills); k1 uses linearity y = rs*(x@Wg - m*colsum) + bc so x streams
// through one MFMA pass with no frag array (~75 live VGPRs).

typedef __attribute__((ext_vector_type(8))) short bf16x8;
typedef __attribute__((ext_vector_type(4))) float f32x4;

__device__ __forceinline__ short f2bf(float f) {
  union { float f; unsigned u; } a; a.f = f;
  unsigned u = a.u;
  u += 0x7fffu + ((u >> 16) & 1u);   // RNE, finite inputs
  return (short)(u >> 16);
}
__device__ __forceinline__ float bf2f(short s) {
  union { unsigned u; float f; } a; a.u = ((unsigned)(unsigned short)s) << 16;
  return a.f;
}
__device__ __forceinline__ float gelu_fast(float h) {
  // 0.5h(1+tanh(u)) = h*sigmoid(2u); 2u*log2e = h*(2.3022082+0.1029471h^2)
  float h2 = h * h;
  float w  = h * (2.3022082f + 0.1029471f * h2);
  float e  = __builtin_amdgcn_exp2f(w);
  float r  = __builtin_amdgcn_rcpf(e + 1.0f);
  return h - h * r;
}
__device__ __forceinline__ void gload_lds16(const void* g, void* l) {
  __builtin_amdgcn_global_load_lds(
      (const __attribute__((address_space(1))) unsigned*)g,
      (__attribute__((address_space(3))) unsigned*)l, 16, 0, 0);
}

// ws layout:
//   WcT  [128][392] @0         (100352)  col n, k-major; = g1[k]*Wc[k][n] bf16
//   W1Ta [256][132] @100352    (67584)   W1[k][n]*g2[k], n<256
//   W2Ta [4][128][68] @167936  (69632)
//   W1Tb [256][132] @237568    (67584)
//   W2Tb [4][128][68] @305152  (69632)
//   bc   [128]f32  @374784     bp + (bkv_v + b1@Wv)@Wp
//   bm1c [512]f32  @375296     bm1 + b2@W1
//   ybuf [4096][2048]bf16 @378880    y then y+partial1 (C-layout)
//   lb   [4096][2048]bf16 @17156096  unscaled LN2(y) (A-frag layout)

// ---------------- prep (707 blocks x 256) ------------------------------------
__global__ void prep(const float* __restrict__ Wkv, const float* __restrict__ bkv,
                     const float* __restrict__ Wp,  const float* __restrict__ bp,
                     const float* __restrict__ W1,  const float* __restrict__ W2,
                     const float* __restrict__ g1,  const float* __restrict__ b1,
                     const float* __restrict__ g2,  const float* __restrict__ b2,
                     const float* __restrict__ bm1,
                     short* __restrict__ WcT, short* __restrict__ W1Ta,
                     short* __restrict__ W1Tb, short* __restrict__ W2Ta,
                     short* __restrict__ W2Tb, float* __restrict__ bc,
                     float* __restrict__ bm1c) {
  const int b = blockIdx.x, tid = threadIdx.x;
  if (b < 192) {                        // WcT fold + g1 scale
    __shared__ float wv[2][128];
    const int kk = tid >> 7, n = tid & 127, k = 2 * b + kk;
    wv[kk][n] = Wkv[k * 256 + 128 + n];
    __syncthreads();
    float s0 = 0, s1 = 0, s2 = 0, s3 = 0;
#pragma unroll 8
    for (int m = 0; m < 128; m += 4) {
      s0 += wv[kk][m]     * Wp[(m)     * 128 + n];
      s1 += wv[kk][m + 1] * Wp[(m + 1) * 128 + n];
      s2 += wv[kk][m + 2] * Wp[(m + 2) * 128 + n];
      s3 += wv[kk][m + 3] * Wp[(m + 3) * 128 + n];
    }
    WcT[n * 392 + k] = f2bf(g1[k] * (s0 + s1 + s2 + s3));
  } else if (b == 192) {                // bc = bp + (bkv_v + b1@Wv)@Wp
    __shared__ float t[128];
    if (tid < 128) {
      float a0 = 0, a1 = 0, a2 = 0, a3 = 0;
#pragma unroll 8
      for (int k = 0; k < 384; k += 4) {
        a0 += b1[k]     * Wkv[(k)     * 256 + 128 + tid];
        a1 += b1[k + 1] * Wkv[(k + 1) * 256 + 128 + tid];
        a2 += b1[k + 2] * Wkv[(k + 2) * 256 + 128 + tid];
        a3 += b1[k + 3] * Wkv[(k + 3) * 256 + 128 + tid];
      }
      t[tid] = a0 + a1 + a2 + a3 + bkv[128 + tid];
    }
    __syncthreads();
    if (tid < 128) {
      float s = bp[tid];
#pragma unroll 8
      for (int m = 0; m < 128; ++m) s += t[m] * Wp[m * 128 + tid];
      bc[tid] = s;
    }
  } else if (b < 449) {                 // W1T halves, rows scaled by g2[k]
    const int id = (b - 193) * 256 + tid;
    const int n = id & 511, k = id >> 9;
    const short v = f2bf(W1[k * 512 + n] * g2[k]);
    if (n < 256) W1Ta[n * 132 + k] = v;
    else         W1Tb[(n - 256) * 132 + k] = v;
  } else if (b < 705) {                 // W2T, ch-chunked halves
    const int id = (b - 449) * 256 + tid;
    const int n = id & 127, k = id >> 7;
    const int ch = k >> 6, kk = k & 63;
    short* dst = (ch < 4) ? W2Ta : W2Tb;
    dst[((ch & 3) * 128 + n) * 68 + kk] = f2bf(W2[k * 128 + n]);
  } else {                              // bm1c = bm1 + b2@W1
    const int h = (b - 705) * 256 + tid;   // [0,512)
    float s = bm1[h];
#pragma unroll 8
    for (int k = 0; k < 128; ++k) s += b2[k] * W1[k * 512 + h];
    bm1c[h] = s;
  }
}

// ---------------- K1: stream-x GEMM + LN folds, 16 waves/block ---------------
__global__ __launch_bounds__(1024)
void k1(const float* __restrict__ x, const short* __restrict__ WcTg,
        const float* __restrict__ bcg,
        short* __restrict__ yb, short* __restrict__ lb) {
  __shared__ __align__(16) short WcT_l[128 * 392];   // 100352 B
  __shared__ float bcf[128], css[128];
  const int tid = threadIdx.x, lane = tid & 63, w = tid >> 6;
  const int q = lane >> 4, c16 = lane & 15;

  for (int c = w; c < 98; c += 16)
    gload_lds16((const char*)WcTg + c * 1024 + lane * 16, (char*)WcT_l + c * 1024);
  if (tid < 32) ((float4*)bcf)[tid] = ((const float4*)bcg)[tid];
  __syncthreads();
  if (tid < 128) {                     // colsum of the exact bf16 weights used
    float s0 = 0, s1 = 0, s2 = 0, s3 = 0;
    const short* row = WcT_l + tid * 392;
#pragma unroll 12
    for (int k = 0; k < 384; k += 4) {
      s0 += bf2f(row[k]); s1 += bf2f(row[k + 1]);
      s2 += bf2f(row[k + 2]); s3 += bf2f(row[k + 3]);
    }
    css[tid] = s0 + s1 + s2 + s3;
  }
  __syncthreads();

  float bcv[8], cs[8];
#pragma unroll
  for (int t = 0; t < 8; ++t) { bcv[t] = bcf[t * 16 + c16]; cs[t] = css[t * 16 + c16]; }

  const long band = (long)blockIdx.x * 16 + w;
  const float* xp = x + (band * 16 + c16) * 384 + q * 8;
  f32x4 yacc[8];
#pragma unroll
  for (int t = 0; t < 8; ++t) yacc[t] = (f32x4){0.f, 0.f, 0.f, 0.f};
  float s = 0.f, sq = 0.f;
#pragma unroll
  for (int ks = 0; ks < 12; ++ks) {     // stream x: stats + MFMA, no frag array
    const float4 va = *(const float4*)(xp + ks * 32);
    const float4 vb = *(const float4*)(xp + ks * 32 + 4);
    s  += va.x + va.y + va.z + va.w + vb.x + vb.y + vb.z + vb.w;
    sq += va.x * va.x + va.y * va.y + va.z * va.z + va.w * va.w
        + vb.x * vb.x + vb.y * vb.y + vb.z * vb.z + vb.w * vb.w;
    bf16x8 f;
    f[0] = f2bf(va.x); f[1] = f2bf(va.y); f[2] = f2bf(va.z); f[3] = f2bf(va.w);
    f[4] = f2bf(vb.x); f[5] = f2bf(vb.y); f[6] = f2bf(vb.z); f[7] = f2bf(vb.w);
#pragma unroll
    for (int t = 0; t < 8; ++t) {
      bf16x8 bfr = *(const bf16x8*)(WcT_l + (t * 16 + c16) * 392 + ks * 32 + q * 8);
      yacc[t] = __builtin_amdgcn_mfma_f32_16x16x32_bf16(f, bfr, yacc[t], 0, 0, 0);
    }
  }
  s  += __shfl_xor(s, 16);  s  += __shfl_xor(s, 32);   // row-c16 stats
  sq += __shfl_xor(sq, 16); sq += __shfl_xor(sq, 32);
  const float mean = s * (1.f / 384.f);
  const float rs = rsqrtf(sq * (1.f / 384.f) - mean * mean + 1e-5f);
  // stats for C-rows (q*4+r) live in lane q*4+r
  float mr[4], rr[4];
#pragma unroll
  for (int r = 0; r < 4; ++r) {
    mr[r] = __shfl(mean, q * 4 + r);
    rr[r] = __shfl(rs,   q * 4 + r);
  }
  // finalize y = rr*(u - mr*colsum) + bc; LN2 stats
  float sm[4] = {0, 0, 0, 0}, sv[4] = {0, 0, 0, 0};
#pragma unroll
  for (int t = 0; t < 8; ++t)
#pragma unroll
    for (int r = 0; r < 4; ++r) {
      const float yv = rr[r] * (yacc[t][r] - mr[r] * cs[t]) + bcv[t];
      yacc[t][r] = yv; sm[r] += yv; sv[r] += yv * yv;
    }
#pragma unroll
  for (int r = 0; r < 4; ++r) {
    sm[r] += __shfl_xor(sm[r], 1); sm[r] += __shfl_xor(sm[r], 2);
    sm[r] += __shfl_xor(sm[r], 4); sm[r] += __shfl_xor(sm[r], 8);
    sv[r] += __shfl_xor(sv[r], 1); sv[r] += __shfl_xor(sv[r], 2);
    sv[r] += __shfl_xor(sv[r], 4); sv[r] += __shfl_xor(sv[r], 8);
  }
  short* ybB = yb + band * 2048;
  short* lbB = lb + band * 2048;
#pragma unroll
  for (int r = 0; r < 4; ++r) {
    const float mn = sm[r] * (1.f / 128.f);
    const float rv = rsqrtf(sv[r] * (1.f / 128.f) - mn * mn + 1e-5f);
    bf16x8 yp;
#pragma unroll
    for (int t = 0; t < 8; ++t) {
      const float yv = yacc[t][r];
      yp[t] = f2bf(yv);
      lbB[((t * 4 + r) * 4 + q) * 16 + c16] = f2bf((yv - mn) * rv);  // g2/b2 folded
    }
    *(bf16x8*)(ybB + ((r * 4 + q) * 16 + c16) * 8) = yp;
  }
}

// ---------------- K2 halves: MLP in 32-hidden sub-chunks, 16 waves/block -----
template <bool FINAL>
__global__ __launch_bounds__(1024)
void k2(const short* __restrict__ lb, short* __restrict__ ybuf,
        const short* __restrict__ W1Tg, const short* __restrict__ W2Tg,
        const float* __restrict__ bm1h, const float* __restrict__ bm2,
        float* __restrict__ out) {
  __shared__ __align__(16) short W1s[256 * 132];    // 67584 B
  __shared__ __align__(16) short W2s[4 * 128 * 68]; // 69632 B
  __shared__ __align__(16) short A3s[16][16 * 36];  // 18432 B, wave-private
  __shared__ float bm1s[256], bm2s[128];
  const int tid = threadIdx.x, lane = tid & 63, w = tid >> 6;
  const int q = lane >> 4, c16 = lane & 15;

  for (int c = w; c < 66; c += 16)
    gload_lds16((const char*)W1Tg + c * 1024 + lane * 16, (char*)W1s + c * 1024);
  for (int c = w; c < 68; c += 16)
    gload_lds16((const char*)W2Tg + c * 1024 + lane * 16, (char*)W2s + c * 1024);
  if (tid < 64) ((float4*)bm1s)[tid] = ((const float4*)bm1h)[tid];
  else if (tid < 96) ((float4*)bm2s)[tid - 64] = ((const float4*)bm2)[tid - 64];
  __syncthreads();   // only barrier

  float bm2v[8];
#pragma unroll
  for (int t = 0; t < 8; ++t) bm2v[t] = bm2s[t * 16 + c16];

  const long band = (long)blockIdx.x * 16 + w;
  const short* lbB = lb + band * 2048;
  short* ybB = ybuf + band * 2048;
  bf16x8 a2f[4];
#pragma unroll
  for (int ks = 0; ks < 4; ++ks) {
    const int t = ks * 2 + (q >> 1);
    a2f[ks] = *(const bf16x8*)(lbB + ((t * 4 + (c16 & 3)) * 4 + (c16 >> 2)) * 16 + (q & 1) * 8);
  }
  f32x4 zacc[8];
#pragma unroll
  for (int t = 0; t < 8; ++t) zacc[t] = (f32x4){0.f, 0.f, 0.f, 0.f};
  short* a3 = A3s[w];

#pragma unroll
  for (int ch = 0; ch < 4; ++ch) {
#pragma unroll
    for (int sub = 0; sub < 2; ++sub) {
      f32x4 hacc[2];
      hacc[0] = (f32x4){0.f, 0.f, 0.f, 0.f};
      hacc[1] = (f32x4){0.f, 0.f, 0.f, 0.f};
#pragma unroll
      for (int ks = 0; ks < 4; ++ks)
#pragma unroll
        for (int tt = 0; tt < 2; ++tt) {
          bf16x8 bfr = *(const bf16x8*)(W1s + (ch * 64 + sub * 32 + tt * 16 + c16) * 132 + ks * 32 + q * 8);
          hacc[tt] = __builtin_amdgcn_mfma_f32_16x16x32_bf16(a2f[ks], bfr, hacc[tt], 0, 0, 0);
        }
#pragma unroll
      for (int tt = 0; tt < 2; ++tt) {
        const float bb = bm1s[ch * 64 + sub * 32 + tt * 16 + c16];
#pragma unroll
        for (int r = 0; r < 4; ++r) {
          const float h = hacc[tt][r] + bb;
          a3[(q * 4 + r) * 36 + tt * 16 + c16] = f2bf(gelu_fast(h));
        }
      }
      asm volatile("s_waitcnt lgkmcnt(0)" ::: "memory");  // in-wave A3 RAW
      bf16x8 af = *(const bf16x8*)(a3 + c16 * 36 + q * 8);
#pragma unroll
      for (int t = 0; t < 8; ++t) {
        bf16x8 bfr = *(const bf16x8*)(W2s + (ch * 128 + t * 16 + c16) * 68 + sub * 32 + q * 8);
        zacc[t] = __builtin_amdgcn_mfma_f32_16x16x32_bf16(af, bfr, zacc[t], 0, 0, 0);
      }
    }
  }
  // ---- epilogue
  bf16x8 yf[4];
#pragma unroll
  for (int r = 0; r < 4; ++r)
    yf[r] = *(const bf16x8*)(ybB + ((r * 4 + q) * 16 + c16) * 8);
  if (!FINAL) {        // k2a: ybuf = y + partial1 (bf16 RMW, own band)
#pragma unroll
    for (int r = 0; r < 4; ++r) {
      bf16x8 zp;
#pragma unroll
      for (int t = 0; t < 8; ++t) zp[t] = f2bf(bf2f(yf[r][t]) + zacc[t][r]);
      *(bf16x8*)(ybB + ((r * 4 + q) * 16 + c16) * 8) = zp;
    }
  } else {             // k2b: out = (y+partial1) + partial2 + bm2
#pragma unroll
    for (int r = 0; r < 4; ++r) {
      const long rowg = band * 16 + q * 4 + r;
#pragma unroll
      for (int t = 0; t < 8; ++t)
        out[rowg * 128 + t * 16 + c16] = bf2f(yf[r][t]) + zacc[t][r] + bm2v[t];
    }
  }
}

extern "C" void kernel_launch(void* const* d_in, const int* in_sizes, int n_in,
                              void* d_out, int out_size, void* d_ws, size_t ws_size,
                              hipStream_t stream) {
  const float* x   = (const float*)d_in[0];
  const float* g1  = (const float*)d_in[1];
  const float* b1  = (const float*)d_in[2];
  // d_in[3]=Wq, [4]=bq, [7]=rpb dead (softmax over size-1 axis == 1)
  const float* Wkv = (const float*)d_in[5];
  const float* bkv = (const float*)d_in[6];
  const float* Wp  = (const float*)d_in[8];
  const float* bp  = (const float*)d_in[9];
  const float* g2  = (const float*)d_in[10];
  const float* b2  = (const float*)d_in[11];
  const float* W1  = (const float*)d_in[12];
  const float* bm1 = (const float*)d_in[13];
  const float* W2  = (const float*)d_in[14];
  const float* bm2 = (const float*)d_in[15];

  char* ws = (char*)d_ws;
  short* WcT  = (short*)(ws + 0);
  short* W1Ta = (short*)(ws + 100352);
  short* W2Ta = (short*)(ws + 167936);
  short* W1Tb = (short*)(ws + 237568);
  short* W2Tb = (short*)(ws + 305152);
  float* bc   = (float*)(ws + 374784);
  float* bm1c = (float*)(ws + 375296);
  short* ybuf = (short*)(ws + 378880);
  short* lb   = (short*)(ws + 17156096);

  prep<<<707, 256, 0, stream>>>(Wkv, bkv, Wp, bp, W1, W2, g1, b1, g2, b2, bm1,
                                WcT, W1Ta, W1Tb, W2Ta, W2Tb, bc, bm1c);
  k1<<<256, 1024, 0, stream>>>(x, WcT, bc, ybuf, lb);
  k2<false><<<256, 1024, 0, stream>>>(lb, ybuf, W1Ta, W2Ta, bm1c, bm2, (float*)d_out);
  k2<true><<<256, 1024, 0, stream>>>(lb, ybuf, W1Tb, W2Tb, bm1c + 256, bm2, (float*)d_out);
}